// Round 8
// baseline (334.454 us; speedup 1.0000x reference)
//
#include <hip/hip_runtime.h>
#include <math.h>

// GCN on 50000 disjoint 21-node hand-skeleton graphs (fixed topology).
// Fused: aggregate-before-matmul, BN folded into W/b, pooling commuted past W3.
// R8: 8 blocks/CU (single-buffered frags, 17.9KB LDS); CPB=2 (6250 blocks,
// short tail); phase1 split compute(A)/write(B) with register carry; x loads
// issued first for cold-miss overlap; all phase-1 indices hoisted.

#define G_TOTAL 50000
#define GPB 4
#define CPB 2                               // chunks per block
#define NBLK (G_TOTAL / (GPB * CPB))        // 6250, exact
#define NCLS 29
#define BN_EPS 1e-5f
#define INV_SQRT2 0.70710678118654752440f
#define ROOT_W 0.21597780504441608f         // (1 + 5/sqrt(2)) / 21

// ws dword layout (unchanged)
#define WS_W1B  0              // 256: [k]{w0,w1,w2,b1f} float4-interleaved
#define WS_B2   256            // 128
#define WS_B3   384            // 32 (29 used)
#define WS_W3T  416            // 3712: W3T [29][128]
#define WS_BF   4128           // 4096: W2 B-frags bf16 [n8][ss2][lane64][4dw]
#define WS_TOTAL (WS_BF + 4096)

#define TSTRIDE 1056           // frag tile stride (1024 + 32 pad)

typedef short s16x8 __attribute__((ext_vector_type(8)));
typedef float f32x4 __attribute__((ext_vector_type(4)));

__device__ __forceinline__ unsigned f2bf_rne(float f) {
    unsigned u = __float_as_uint(f);
    return (u + 0x7FFFu + ((u >> 16) & 1u)) >> 16;
}

__global__ void prep_kernel(const float* __restrict__ W1, const float* __restrict__ b1,
                            const float* __restrict__ g1, const float* __restrict__ be1,
                            const float* __restrict__ m1, const float* __restrict__ v1,
                            const float* __restrict__ W2, const float* __restrict__ b2,
                            const float* __restrict__ g2, const float* __restrict__ be2,
                            const float* __restrict__ m2, const float* __restrict__ v2,
                            const float* __restrict__ W3, const float* __restrict__ b3,
                            float* __restrict__ ws) {
    int t = blockIdx.x * blockDim.x + threadIdx.x;
    if (t < 256) {                              // W1B interleave
        int k = t >> 2, comp = t & 3;
        float s = g1[k] * rsqrtf(v1[k] + BN_EPS);
        float v;
        if (comp < 3) v = W1[comp * 64 + k] * s;
        else          v = (b1[k] - m1[k]) * s + be1[k];
        ws[WS_W1B + t] = v;
    } else if (t < 384) {                       // b2f
        int j = t - 256;
        float s = g2[j] * rsqrtf(v2[j] + BN_EPS);
        ws[WS_B2 + j] = (b2[j] - m2[j]) * s + be2[j];
    } else if (t < 416) {                       // b3 (pad 32)
        int j = t - 384;
        ws[WS_B3 + j] = (j < NCLS) ? b3[j] : 0.f;
    } else if (t < WS_BF) {                     // W3T[c][k] = W3[k*29+c]
        int i = t - WS_W3T;
        if (i < 3712) {
            int c = i >> 7, k = i & 127;
            ws[WS_W3T + i] = W3[k * NCLS + c];
        }
    } else if (t < WS_TOTAL) {                  // B-frags of W2f (bf16 RNE)
        int i = t - WS_BF;                      // dword index
        int d  = i & 3;
        int l  = (i >> 2) & 63;
        int ss = (i >> 8) & 1;
        int n  = i >> 9;                        // 0..7
        int kg = l >> 4, r = l & 15;
        int c = 16 * n + r;
        float sc = g2[c] * rsqrtf(v2[c] + BN_EPS);
        int k0 = 32 * ss + 8 * kg + 2 * d;
        unsigned h0 = f2bf_rne(W2[k0 * 128 + c] * sc);
        unsigned h1 = f2bf_rne(W2[(k0 + 1) * 128 + c] * sc);
        ((unsigned*)ws)[WS_BF + i] = (h1 << 16) | h0;
    }
}

__global__ __launch_bounds__(256, 8)
void gcn_main(const float* __restrict__ x, const float* __restrict__ ws,
              float* __restrict__ out) {
    __shared__ __align__(16) char sFrag[12 * TSTRIDE];     // 12672 B (single buffer)
    __shared__ __align__(16) float4 sW1B[64];              // 1 KB
    __shared__ __align__(16) float4 sX[2][64];             // 2 KB
    __shared__ __align__(16) float sPool[4 * 132];         // 2112 B

    const int tid = threadIdx.x;
    const int lane = tid & 63;
    const int w = tid >> 6;
    const int r = lane & 15;
    const int lg = lane >> 4;
    const long long cbase = (long long)blockIdx.x * CPB;

    // ---- issue x loads FIRST (cold-miss overlap), disjoint thread groups ----
    if (tid >= 192 && tid < 255)
        sX[0][tid - 192] = ((const float4*)(x + cbase * 252))[tid - 192];
    if (tid >= 128 && tid < 191)
        sX[1][tid - 128] = ((const float4*)(x + (cbase + 1) * 252))[tid - 128];
    if (tid < 64) sW1B[tid] = ((const float4*)ws)[tid];
    if (tid < 132)                              // zero pad rows of tiles 10,11
        *(float4*)(sFrag + 10 * TSTRIDE + tid * 16) = make_float4(0.f, 0.f, 0.f, 0.f);

    // ---- per-thread constants held across chunks ----
    const uint4* wsB = (const uint4*)((const unsigned*)ws + WS_BF);
    const uint4 B00 = wsB[((2*w+0)*2 + 0)*64 + lane];
    const uint4 B01 = wsB[((2*w+0)*2 + 1)*64 + lane];
    const uint4 B10 = wsB[((2*w+1)*2 + 0)*64 + lane];
    const uint4 B11 = wsB[((2*w+1)*2 + 1)*64 + lane];
    const float b2c0 = ws[WS_B2 + 32*w + r];
    const float b2c1 = ws[WS_B2 + 32*w + 16 + r];
    const int cc = lane >> 1;                   // phase-3 class (lane<58)
    const int h3 = lane & 1;                    // phase-3 k-half
    const float b3r = ws[WS_B3 + (cc < NCLS ? cc : 0)];
    const float* w3base = ws + WS_W3T + cc * 128 + 64 * h3;

    // ---- hoisted phase-1 constants (tid<168) ----
    const int node = tid >> 1;                  // 0..83 (for tid<168)
    const int s1v = tid & 1;
    const int k0q = s1v * 32;
    const int g4 = (node * 3121) >> 16;         // node/21
    const int p  = node - 21 * g4;
    const int dist  = (p == 0) ? 0 : (((p & 3) == 1) ? p : 1);
    const float cw  = ((p & 3) == 1) ? INV_SQRT2 : 0.5f;
    const int jp = p - dist;
    const int dist2 = (jp == 0) ? 0 : (((jp & 3) == 1) ? jp : 1);
    const float cw2 = ((jp & 3) == 1) ? INV_SQRT2 : 0.5f;
    const int xoff = node * 3;
    char* const fragW = sFrag + ((p >> 2) * 2 + s1v) * TSTRIDE
                      + (4 * g4 + (p & 3)) * 16;

    unsigned dws[16];

    // compute az[k0q..k0q+31] for chunk in sX[buf] -> packed dws[16]
    auto p1_compute = [&](int buf) {
        const float* xs = (const float*)&sX[buf][0] + xoff;
        const float* xq = xs - dist * 3;
        const float* xg = xq - dist2 * 3;
        const float ax0 = fmaf(cw,  xq[0], 0.5f * xs[0]);
        const float ax1 = fmaf(cw,  xq[1], 0.5f * xs[1]);
        const float ax2 = fmaf(cw,  xq[2], 0.5f * xs[2]);
        const float bx0 = fmaf(cw2, xg[0], 0.5f * xq[0]);
        const float bx1 = fmaf(cw2, xg[1], 0.5f * xq[1]);
        const float bx2 = fmaf(cw2, xg[2], 0.5f * xq[2]);
        #pragma unroll
        for (int q = 0; q < 16; ++q) {
            float azv[2];
            #pragma unroll
            for (int e = 0; e < 2; ++e) {
                const float4 wv = sW1B[k0q + 2*q + e];
                float ts = fmaf(ax0, wv.x, wv.w);
                ts = fmaf(ax1, wv.y, ts);
                ts = fmaf(ax2, wv.z, ts);
                ts = fmaxf(ts, 0.f);                    // z[self]
                float tp = fmaf(bx0, wv.x, wv.w);
                tp = fmaf(bx1, wv.y, tp);
                tp = fmaf(bx2, wv.z, tp);
                tp = fmaxf(tp, 0.f);                    // z[parent]
                azv[e] = fmaf(cw, tp, 0.5f * ts);       // root: 0.5+0.5
            }
            dws[q] = __builtin_amdgcn_perm(__float_as_uint(azv[1]),
                                           __float_as_uint(azv[0]), 0x07060302u);
        }
    };
    auto p1_write = [&]() {
        #pragma unroll
        for (int q = 0; q < 4; ++q)
            *(uint4*)(fragW + q * 256) =
                make_uint4(dws[4*q], dws[4*q+1], dws[4*q+2], dws[4*q+3]);
    };

    auto mfma_pool = [&]() {
        const char* fragA = sFrag + lane * 16;
        float pg0 = 0.f, pg1 = 0.f;
        #pragma unroll
        for (int m = 0; m < 6; ++m) {
            const s16x8 A0 = *(const s16x8*)(fragA + (2*m + 0) * TSTRIDE);
            const s16x8 A1 = *(const s16x8*)(fragA + (2*m + 1) * TSTRIDE);
            f32x4 acc0 = {0.f, 0.f, 0.f, 0.f};
            f32x4 acc1 = {0.f, 0.f, 0.f, 0.f};
            acc0 = __builtin_amdgcn_mfma_f32_16x16x32_bf16(A0, *(const s16x8*)&B00, acc0, 0, 0, 0);
            acc0 = __builtin_amdgcn_mfma_f32_16x16x32_bf16(A1, *(const s16x8*)&B01, acc0, 0, 0, 0);
            acc1 = __builtin_amdgcn_mfma_f32_16x16x32_bf16(A0, *(const s16x8*)&B10, acc1, 0, 0, 0);
            acc1 = __builtin_amdgcn_mfma_f32_16x16x32_bf16(A1, *(const s16x8*)&B11, acc1, 0, 0, 0);
            #pragma unroll
            for (int i = 0; i < 4; ++i) {
                const int pp = 4*m + i;
                if (pp < 21) {
                    const float wgt = (pp == 0) ? ROOT_W
                                    : (((pp & 3) == 0) ? (0.5f / 21.f) : (1.f / 21.f));
                    pg0 = fmaf(wgt, fmaxf(acc0[i] + b2c0, 0.f), pg0);
                    pg1 = fmaf(wgt, fmaxf(acc1[i] + b2c1, 0.f), pg1);
                }
            }
        }
        sPool[lg * 132 + 32*w + r]      = pg0;
        sPool[lg * 132 + 32*w + 16 + r] = pg1;
    };

    auto p3_out = [&](int ck) {
        float v = -1e30f;
        if (lane < 2 * NCLS) {
            const float4* pp = (const float4*)&sPool[w * 132 + 64 * h3];
            const float4* w3 = (const float4*)w3base;
            float acc3 = 0.f;
            #pragma unroll
            for (int q = 0; q < 16; ++q) {
                const float4 pv = pp[q];
                const float4 wv = w3[q];
                acc3 = fmaf(pv.x, wv.x, acc3);
                acc3 = fmaf(pv.y, wv.y, acc3);
                acc3 = fmaf(pv.z, wv.z, acc3);
                acc3 = fmaf(pv.w, wv.w, acc3);
            }
            v = acc3;
        }
        v += __shfl_xor(v, 1);              // combine k-halves -> full 128-dot
        if (lane < 2 * NCLS) v += b3r;
        float m = v;
        m = fmaxf(m, __shfl_xor(m, 2));
        m = fmaxf(m, __shfl_xor(m, 4));
        m = fmaxf(m, __shfl_xor(m, 8));
        m = fmaxf(m, __shfl_xor(m, 16));
        m = fmaxf(m, __shfl_xor(m, 32));
        float e = (lane < 2 * NCLS) ? __expf(v - m) : 0.f;
        float ss = e;
        ss += __shfl_xor(ss, 2);
        ss += __shfl_xor(ss, 4);
        ss += __shfl_xor(ss, 8);
        ss += __shfl_xor(ss, 16);
        ss += __shfl_xor(ss, 32);
        if (h3 == 0 && lane < 2 * NCLS)
            out[((cbase + ck) * GPB + w) * NCLS + cc] = v - m - __logf(ss);
    };

    __syncthreads();                        // staging done
    if (tid < 168) { p1_compute(0); p1_write(); }
    __syncthreads();                        // frag[0] ready

    // ---- chunk 0 ----
    mfma_pool();                            // MFMA on frag[0]
    if (tid < 168) p1_compute(1);           // overlapped VALU (regs only)
    __syncthreads();                        // MFMA reads done, pool[0] ready
    if (tid < 168) p1_write();              // frag <- chunk1
    p3_out(0);
    __syncthreads();                        // frag[1] ready, pool reads done

    // ---- chunk 1 ----
    mfma_pool();
    __syncthreads();                        // pool[1] ready
    p3_out(1);
}

extern "C" void kernel_launch(void* const* d_in, const int* in_sizes, int n_in,
                              void* d_out, int out_size, void* d_ws, size_t ws_size,
                              hipStream_t stream) {
    const float* x   = (const float*)d_in[0];
    const float* W1  = (const float*)d_in[1];
    const float* b1  = (const float*)d_in[2];
    const float* g1  = (const float*)d_in[3];
    const float* be1 = (const float*)d_in[4];
    const float* m1  = (const float*)d_in[5];
    const float* v1  = (const float*)d_in[6];
    const float* W2  = (const float*)d_in[7];
    const float* b2  = (const float*)d_in[8];
    const float* g2  = (const float*)d_in[9];
    const float* be2 = (const float*)d_in[10];
    const float* m2  = (const float*)d_in[11];
    const float* v2  = (const float*)d_in[12];
    const float* W3  = (const float*)d_in[13];
    const float* b3  = (const float*)d_in[14];
    float* out = (float*)d_out;
    float* ws  = (float*)d_ws;

    prep_kernel<<<(WS_TOTAL + 255) / 256, 256, 0, stream>>>(
        W1, b1, g1, be1, m1, v1, W2, b2, g2, be2, m2, v2, W3, b3, ws);

    gcn_main<<<NBLK, 256, 0, stream>>>(x, ws, out);
}

// Round 9
// 268.667 us; speedup vs baseline: 1.2449x; 1.2449x over previous
//
#include <hip/hip_runtime.h>
#include <math.h>

// GCN on 50000 disjoint 21-node hand-skeleton graphs (fixed topology).
// Fused: aggregate-before-matmul, BN folded into W/b, pooling commuted past W3.
// R9: R8 pipeline unchanged; __launch_bounds__(256,6) to undo the R8 spill
// (64-VGPR cap forced dws/B-frag scratch spills -> 0.9 GB HBM traffic).
// 6 blocks/CU (VGPR-bound), LDS 17.9KB, CPB=2, phase1 compute/write split.

#define G_TOTAL 50000
#define GPB 4
#define CPB 2                               // chunks per block
#define NBLK (G_TOTAL / (GPB * CPB))        // 6250, exact
#define NCLS 29
#define BN_EPS 1e-5f
#define INV_SQRT2 0.70710678118654752440f
#define ROOT_W 0.21597780504441608f         // (1 + 5/sqrt(2)) / 21

// ws dword layout (unchanged)
#define WS_W1B  0              // 256: [k]{w0,w1,w2,b1f} float4-interleaved
#define WS_B2   256            // 128
#define WS_B3   384            // 32 (29 used)
#define WS_W3T  416            // 3712: W3T [29][128]
#define WS_BF   4128           // 4096: W2 B-frags bf16 [n8][ss2][lane64][4dw]
#define WS_TOTAL (WS_BF + 4096)

#define TSTRIDE 1056           // frag tile stride (1024 + 32 pad)

typedef short s16x8 __attribute__((ext_vector_type(8)));
typedef float f32x4 __attribute__((ext_vector_type(4)));

__device__ __forceinline__ unsigned f2bf_rne(float f) {
    unsigned u = __float_as_uint(f);
    return (u + 0x7FFFu + ((u >> 16) & 1u)) >> 16;
}

__global__ void prep_kernel(const float* __restrict__ W1, const float* __restrict__ b1,
                            const float* __restrict__ g1, const float* __restrict__ be1,
                            const float* __restrict__ m1, const float* __restrict__ v1,
                            const float* __restrict__ W2, const float* __restrict__ b2,
                            const float* __restrict__ g2, const float* __restrict__ be2,
                            const float* __restrict__ m2, const float* __restrict__ v2,
                            const float* __restrict__ W3, const float* __restrict__ b3,
                            float* __restrict__ ws) {
    int t = blockIdx.x * blockDim.x + threadIdx.x;
    if (t < 256) {                              // W1B interleave
        int k = t >> 2, comp = t & 3;
        float s = g1[k] * rsqrtf(v1[k] + BN_EPS);
        float v;
        if (comp < 3) v = W1[comp * 64 + k] * s;
        else          v = (b1[k] - m1[k]) * s + be1[k];
        ws[WS_W1B + t] = v;
    } else if (t < 384) {                       // b2f
        int j = t - 256;
        float s = g2[j] * rsqrtf(v2[j] + BN_EPS);
        ws[WS_B2 + j] = (b2[j] - m2[j]) * s + be2[j];
    } else if (t < 416) {                       // b3 (pad 32)
        int j = t - 384;
        ws[WS_B3 + j] = (j < NCLS) ? b3[j] : 0.f;
    } else if (t < WS_BF) {                     // W3T[c][k] = W3[k*29+c]
        int i = t - WS_W3T;
        if (i < 3712) {
            int c = i >> 7, k = i & 127;
            ws[WS_W3T + i] = W3[k * NCLS + c];
        }
    } else if (t < WS_TOTAL) {                  // B-frags of W2f (bf16 RNE)
        int i = t - WS_BF;                      // dword index
        int d  = i & 3;
        int l  = (i >> 2) & 63;
        int ss = (i >> 8) & 1;
        int n  = i >> 9;                        // 0..7
        int kg = l >> 4, r = l & 15;
        int c = 16 * n + r;
        float sc = g2[c] * rsqrtf(v2[c] + BN_EPS);
        int k0 = 32 * ss + 8 * kg + 2 * d;
        unsigned h0 = f2bf_rne(W2[k0 * 128 + c] * sc);
        unsigned h1 = f2bf_rne(W2[(k0 + 1) * 128 + c] * sc);
        ((unsigned*)ws)[WS_BF + i] = (h1 << 16) | h0;
    }
}

__global__ __launch_bounds__(256, 6)
void gcn_main(const float* __restrict__ x, const float* __restrict__ ws,
              float* __restrict__ out) {
    __shared__ __align__(16) char sFrag[12 * TSTRIDE];     // 12672 B (single buffer)
    __shared__ __align__(16) float4 sW1B[64];              // 1 KB
    __shared__ __align__(16) float4 sX[2][64];             // 2 KB
    __shared__ __align__(16) float sPool[4 * 132];         // 2112 B

    const int tid = threadIdx.x;
    const int lane = tid & 63;
    const int w = tid >> 6;
    const int r = lane & 15;
    const int lg = lane >> 4;
    const long long cbase = (long long)blockIdx.x * CPB;

    // ---- issue x loads FIRST (cold-miss overlap), disjoint thread groups ----
    if (tid >= 192 && tid < 255)
        sX[0][tid - 192] = ((const float4*)(x + cbase * 252))[tid - 192];
    if (tid >= 128 && tid < 191)
        sX[1][tid - 128] = ((const float4*)(x + (cbase + 1) * 252))[tid - 128];
    if (tid < 64) sW1B[tid] = ((const float4*)ws)[tid];
    if (tid < 132)                              // zero pad rows of tiles 10,11
        *(float4*)(sFrag + 10 * TSTRIDE + tid * 16) = make_float4(0.f, 0.f, 0.f, 0.f);

    // ---- per-thread constants held across chunks ----
    const uint4* wsB = (const uint4*)((const unsigned*)ws + WS_BF);
    const uint4 B00 = wsB[((2*w+0)*2 + 0)*64 + lane];
    const uint4 B01 = wsB[((2*w+0)*2 + 1)*64 + lane];
    const uint4 B10 = wsB[((2*w+1)*2 + 0)*64 + lane];
    const uint4 B11 = wsB[((2*w+1)*2 + 1)*64 + lane];
    const float b2c0 = ws[WS_B2 + 32*w + r];
    const float b2c1 = ws[WS_B2 + 32*w + 16 + r];
    const int cc = lane >> 1;                   // phase-3 class (lane<58)
    const int h3 = lane & 1;                    // phase-3 k-half
    const float b3r = ws[WS_B3 + (cc < NCLS ? cc : 0)];
    const float* w3base = ws + WS_W3T + cc * 128 + 64 * h3;

    // ---- hoisted phase-1 constants (tid<168) ----
    const int node = tid >> 1;                  // 0..83 (for tid<168)
    const int s1v = tid & 1;
    const int k0q = s1v * 32;
    const int g4 = (node * 3121) >> 16;         // node/21
    const int p  = node - 21 * g4;
    const int dist  = (p == 0) ? 0 : (((p & 3) == 1) ? p : 1);
    const float cw  = ((p & 3) == 1) ? INV_SQRT2 : 0.5f;
    const int jp = p - dist;
    const int dist2 = (jp == 0) ? 0 : (((jp & 3) == 1) ? jp : 1);
    const float cw2 = ((jp & 3) == 1) ? INV_SQRT2 : 0.5f;
    const int xoff = node * 3;
    char* const fragW = sFrag + ((p >> 2) * 2 + s1v) * TSTRIDE
                      + (4 * g4 + (p & 3)) * 16;

    unsigned dws[16];

    // compute az[k0q..k0q+31] for chunk in sX[buf] -> packed dws[16]
    auto p1_compute = [&](int buf) {
        const float* xs = (const float*)&sX[buf][0] + xoff;
        const float* xq = xs - dist * 3;
        const float* xg = xq - dist2 * 3;
        const float ax0 = fmaf(cw,  xq[0], 0.5f * xs[0]);
        const float ax1 = fmaf(cw,  xq[1], 0.5f * xs[1]);
        const float ax2 = fmaf(cw,  xq[2], 0.5f * xs[2]);
        const float bx0 = fmaf(cw2, xg[0], 0.5f * xq[0]);
        const float bx1 = fmaf(cw2, xg[1], 0.5f * xq[1]);
        const float bx2 = fmaf(cw2, xg[2], 0.5f * xq[2]);
        #pragma unroll
        for (int q = 0; q < 16; ++q) {
            float azv[2];
            #pragma unroll
            for (int e = 0; e < 2; ++e) {
                const float4 wv = sW1B[k0q + 2*q + e];
                float ts = fmaf(ax0, wv.x, wv.w);
                ts = fmaf(ax1, wv.y, ts);
                ts = fmaf(ax2, wv.z, ts);
                ts = fmaxf(ts, 0.f);                    // z[self]
                float tp = fmaf(bx0, wv.x, wv.w);
                tp = fmaf(bx1, wv.y, tp);
                tp = fmaf(bx2, wv.z, tp);
                tp = fmaxf(tp, 0.f);                    // z[parent]
                azv[e] = fmaf(cw, tp, 0.5f * ts);       // root: 0.5+0.5
            }
            dws[q] = __builtin_amdgcn_perm(__float_as_uint(azv[1]),
                                           __float_as_uint(azv[0]), 0x07060302u);
        }
    };
    auto p1_write = [&]() {
        #pragma unroll
        for (int q = 0; q < 4; ++q)
            *(uint4*)(fragW + q * 256) =
                make_uint4(dws[4*q], dws[4*q+1], dws[4*q+2], dws[4*q+3]);
    };

    auto mfma_pool = [&]() {
        const char* fragA = sFrag + lane * 16;
        float pg0 = 0.f, pg1 = 0.f;
        #pragma unroll
        for (int m = 0; m < 6; ++m) {
            const s16x8 A0 = *(const s16x8*)(fragA + (2*m + 0) * TSTRIDE);
            const s16x8 A1 = *(const s16x8*)(fragA + (2*m + 1) * TSTRIDE);
            f32x4 acc0 = {0.f, 0.f, 0.f, 0.f};
            f32x4 acc1 = {0.f, 0.f, 0.f, 0.f};
            acc0 = __builtin_amdgcn_mfma_f32_16x16x32_bf16(A0, *(const s16x8*)&B00, acc0, 0, 0, 0);
            acc0 = __builtin_amdgcn_mfma_f32_16x16x32_bf16(A1, *(const s16x8*)&B01, acc0, 0, 0, 0);
            acc1 = __builtin_amdgcn_mfma_f32_16x16x32_bf16(A0, *(const s16x8*)&B10, acc1, 0, 0, 0);
            acc1 = __builtin_amdgcn_mfma_f32_16x16x32_bf16(A1, *(const s16x8*)&B11, acc1, 0, 0, 0);
            #pragma unroll
            for (int i = 0; i < 4; ++i) {
                const int pp = 4*m + i;
                if (pp < 21) {
                    const float wgt = (pp == 0) ? ROOT_W
                                    : (((pp & 3) == 0) ? (0.5f / 21.f) : (1.f / 21.f));
                    pg0 = fmaf(wgt, fmaxf(acc0[i] + b2c0, 0.f), pg0);
                    pg1 = fmaf(wgt, fmaxf(acc1[i] + b2c1, 0.f), pg1);
                }
            }
        }
        sPool[lg * 132 + 32*w + r]      = pg0;
        sPool[lg * 132 + 32*w + 16 + r] = pg1;
    };

    auto p3_out = [&](int ck) {
        float v = -1e30f;
        if (lane < 2 * NCLS) {
            const float4* pp = (const float4*)&sPool[w * 132 + 64 * h3];
            const float4* w3 = (const float4*)w3base;
            float acc3 = 0.f;
            #pragma unroll
            for (int q = 0; q < 16; ++q) {
                const float4 pv = pp[q];
                const float4 wv = w3[q];
                acc3 = fmaf(pv.x, wv.x, acc3);
                acc3 = fmaf(pv.y, wv.y, acc3);
                acc3 = fmaf(pv.z, wv.z, acc3);
                acc3 = fmaf(pv.w, wv.w, acc3);
            }
            v = acc3;
        }
        v += __shfl_xor(v, 1);              // combine k-halves -> full 128-dot
        if (lane < 2 * NCLS) v += b3r;
        float m = v;
        m = fmaxf(m, __shfl_xor(m, 2));
        m = fmaxf(m, __shfl_xor(m, 4));
        m = fmaxf(m, __shfl_xor(m, 8));
        m = fmaxf(m, __shfl_xor(m, 16));
        m = fmaxf(m, __shfl_xor(m, 32));
        float e = (lane < 2 * NCLS) ? __expf(v - m) : 0.f;
        float ss = e;
        ss += __shfl_xor(ss, 2);
        ss += __shfl_xor(ss, 4);
        ss += __shfl_xor(ss, 8);
        ss += __shfl_xor(ss, 16);
        ss += __shfl_xor(ss, 32);
        if (h3 == 0 && lane < 2 * NCLS)
            out[((cbase + ck) * GPB + w) * NCLS + cc] = v - m - __logf(ss);
    };

    __syncthreads();                        // staging done
    if (tid < 168) { p1_compute(0); p1_write(); }
    __syncthreads();                        // frag[0] ready

    // ---- chunk 0 ----
    mfma_pool();                            // MFMA on frag[0]
    if (tid < 168) p1_compute(1);           // overlapped VALU (regs only)
    __syncthreads();                        // MFMA reads done, pool[0] ready
    if (tid < 168) p1_write();              // frag <- chunk1
    p3_out(0);
    __syncthreads();                        // frag[1] ready, pool reads done

    // ---- chunk 1 ----
    mfma_pool();
    __syncthreads();                        // pool[1] ready
    p3_out(1);
}

extern "C" void kernel_launch(void* const* d_in, const int* in_sizes, int n_in,
                              void* d_out, int out_size, void* d_ws, size_t ws_size,
                              hipStream_t stream) {
    const float* x   = (const float*)d_in[0];
    const float* W1  = (const float*)d_in[1];
    const float* b1  = (const float*)d_in[2];
    const float* g1  = (const float*)d_in[3];
    const float* be1 = (const float*)d_in[4];
    const float* m1  = (const float*)d_in[5];
    const float* v1  = (const float*)d_in[6];
    const float* W2  = (const float*)d_in[7];
    const float* b2  = (const float*)d_in[8];
    const float* g2  = (const float*)d_in[9];
    const float* be2 = (const float*)d_in[10];
    const float* m2  = (const float*)d_in[11];
    const float* v2  = (const float*)d_in[12];
    const float* W3  = (const float*)d_in[13];
    const float* b3  = (const float*)d_in[14];
    float* out = (float*)d_out;
    float* ws  = (float*)d_ws;

    prep_kernel<<<(WS_TOTAL + 255) / 256, 256, 0, stream>>>(
        W1, b1, g1, be1, m1, v1, W2, b2, g2, be2, m2, v2, W3, b3, ws);

    gcn_main<<<NBLK, 256, 0, stream>>>(x, ws, out);
}

// Round 10
// 268.004 us; speedup vs baseline: 1.2479x; 1.0025x over previous
//
#include <hip/hip_runtime.h>
#include <math.h>

// GCN on 50000 disjoint 21-node hand-skeleton graphs (fixed topology).
// Fused: aggregate-before-matmul, BN folded into W/b, pooling commuted past W3.
// R10: R8 pipeline, but cross-barrier A-frag carry in NAMED registers
// (straight-line macro -> 16 named unsigneds -> 4 named uint4) — no arrays,
// no runtime indexing, so no local-memory demotion (the R8/R9 0.5-0.9 GB
// scratch traffic). launch_bounds(256,6); LDS 17.9KB; CPB=2.

#define G_TOTAL 50000
#define GPB 4
#define CPB 2                               // chunks per block
#define NBLK (G_TOTAL / (GPB * CPB))        // 6250, exact
#define NCLS 29
#define BN_EPS 1e-5f
#define INV_SQRT2 0.70710678118654752440f
#define ROOT_W 0.21597780504441608f         // (1 + 5/sqrt(2)) / 21

// ws dword layout (unchanged)
#define WS_W1B  0              // 256: [k]{w0,w1,w2,b1f} float4-interleaved
#define WS_B2   256            // 128
#define WS_B3   384            // 32 (29 used)
#define WS_W3T  416            // 3712: W3T [29][128]
#define WS_BF   4128           // 4096: W2 B-frags bf16 [n8][ss2][lane64][4dw]
#define WS_TOTAL (WS_BF + 4096)

#define TSTRIDE 1056           // frag tile stride (1024 + 32 pad)

typedef short s16x8 __attribute__((ext_vector_type(8)));
typedef float f32x4 __attribute__((ext_vector_type(4)));

__device__ __forceinline__ unsigned f2bf_rne(float f) {
    unsigned u = __float_as_uint(f);
    return (u + 0x7FFFu + ((u >> 16) & 1u)) >> 16;
}

__global__ void prep_kernel(const float* __restrict__ W1, const float* __restrict__ b1,
                            const float* __restrict__ g1, const float* __restrict__ be1,
                            const float* __restrict__ m1, const float* __restrict__ v1,
                            const float* __restrict__ W2, const float* __restrict__ b2,
                            const float* __restrict__ g2, const float* __restrict__ be2,
                            const float* __restrict__ m2, const float* __restrict__ v2,
                            const float* __restrict__ W3, const float* __restrict__ b3,
                            float* __restrict__ ws) {
    int t = blockIdx.x * blockDim.x + threadIdx.x;
    if (t < 256) {                              // W1B interleave
        int k = t >> 2, comp = t & 3;
        float s = g1[k] * rsqrtf(v1[k] + BN_EPS);
        float v;
        if (comp < 3) v = W1[comp * 64 + k] * s;
        else          v = (b1[k] - m1[k]) * s + be1[k];
        ws[WS_W1B + t] = v;
    } else if (t < 384) {                       // b2f
        int j = t - 256;
        float s = g2[j] * rsqrtf(v2[j] + BN_EPS);
        ws[WS_B2 + j] = (b2[j] - m2[j]) * s + be2[j];
    } else if (t < 416) {                       // b3 (pad 32)
        int j = t - 384;
        ws[WS_B3 + j] = (j < NCLS) ? b3[j] : 0.f;
    } else if (t < WS_BF) {                     // W3T[c][k] = W3[k*29+c]
        int i = t - WS_W3T;
        if (i < 3712) {
            int c = i >> 7, k = i & 127;
            ws[WS_W3T + i] = W3[k * NCLS + c];
        }
    } else if (t < WS_TOTAL) {                  // B-frags of W2f (bf16 RNE)
        int i = t - WS_BF;                      // dword index
        int d  = i & 3;
        int l  = (i >> 2) & 63;
        int ss = (i >> 8) & 1;
        int n  = i >> 9;                        // 0..7
        int kg = l >> 4, r = l & 15;
        int c = 16 * n + r;
        float sc = g2[c] * rsqrtf(v2[c] + BN_EPS);
        int k0 = 32 * ss + 8 * kg + 2 * d;
        unsigned h0 = f2bf_rne(W2[k0 * 128 + c] * sc);
        unsigned h1 = f2bf_rne(W2[(k0 + 1) * 128 + c] * sc);
        ((unsigned*)ws)[WS_BF + i] = (h1 << 16) | h0;
    }
}

// straight-line pack of two az values (k = k0q+2*qi, k0q+2*qi+1) -> one dword
#define PKPAIR(qi, dst) do {                                                   \
    const float4 wvA = sW1B[k0q + 2*(qi)];                                     \
    float tsA = fmaf(ax0, wvA.x, wvA.w);                                       \
    tsA = fmaf(ax1, wvA.y, tsA); tsA = fmaf(ax2, wvA.z, tsA);                  \
    tsA = fmaxf(tsA, 0.f);                                                     \
    float tpA = fmaf(bx0, wvA.x, wvA.w);                                       \
    tpA = fmaf(bx1, wvA.y, tpA); tpA = fmaf(bx2, wvA.z, tpA);                  \
    tpA = fmaxf(tpA, 0.f);                                                     \
    const float azA = fmaf(cw, tpA, 0.5f * tsA);                               \
    const float4 wvB = sW1B[k0q + 2*(qi) + 1];                                 \
    float tsB = fmaf(ax0, wvB.x, wvB.w);                                       \
    tsB = fmaf(ax1, wvB.y, tsB); tsB = fmaf(ax2, wvB.z, tsB);                  \
    tsB = fmaxf(tsB, 0.f);                                                     \
    float tpB = fmaf(bx0, wvB.x, wvB.w);                                       \
    tpB = fmaf(bx1, wvB.y, tpB); tpB = fmaf(bx2, wvB.z, tpB);                  \
    tpB = fmaxf(tpB, 0.f);                                                     \
    const float azB = fmaf(cw, tpB, 0.5f * tsB);                               \
    dst = __builtin_amdgcn_perm(__float_as_uint(azB), __float_as_uint(azA),    \
                                0x07060302u);                                  \
} while (0)

__global__ __launch_bounds__(256, 6)
void gcn_main(const float* __restrict__ x, const float* __restrict__ ws,
              float* __restrict__ out) {
    __shared__ __align__(16) char sFrag[12 * TSTRIDE];     // 12672 B (single buffer)
    __shared__ __align__(16) float4 sW1B[64];              // 1 KB
    __shared__ __align__(16) float4 sX[2][64];             // 2 KB
    __shared__ __align__(16) float sPool[4 * 132];         // 2112 B

    const int tid = threadIdx.x;
    const int lane = tid & 63;
    const int w = tid >> 6;
    const int r = lane & 15;
    const int lg = lane >> 4;
    const long long cbase = (long long)blockIdx.x * CPB;

    // ---- issue x loads FIRST (cold-miss overlap), disjoint thread groups ----
    if (tid >= 192 && tid < 255)
        sX[0][tid - 192] = ((const float4*)(x + cbase * 252))[tid - 192];
    if (tid >= 128 && tid < 191)
        sX[1][tid - 128] = ((const float4*)(x + (cbase + 1) * 252))[tid - 128];
    if (tid < 64) sW1B[tid] = ((const float4*)ws)[tid];
    if (tid < 132)                              // zero pad rows of tiles 10,11
        *(float4*)(sFrag + 10 * TSTRIDE + tid * 16) = make_float4(0.f, 0.f, 0.f, 0.f);

    // ---- per-thread constants held across chunks ----
    const uint4* wsB = (const uint4*)((const unsigned*)ws + WS_BF);
    const uint4 B00 = wsB[((2*w+0)*2 + 0)*64 + lane];
    const uint4 B01 = wsB[((2*w+0)*2 + 1)*64 + lane];
    const uint4 B10 = wsB[((2*w+1)*2 + 0)*64 + lane];
    const uint4 B11 = wsB[((2*w+1)*2 + 1)*64 + lane];
    const float b2c0 = ws[WS_B2 + 32*w + r];
    const float b2c1 = ws[WS_B2 + 32*w + 16 + r];
    const int cc = lane >> 1;                   // phase-3 class (lane<58)
    const int h3 = lane & 1;                    // phase-3 k-half
    const float b3r = ws[WS_B3 + (cc < NCLS ? cc : 0)];
    const float* w3base = ws + WS_W3T + cc * 128 + 64 * h3;

    // ---- hoisted phase-1 constants (tid<168) ----
    const int node = tid >> 1;                  // 0..83 (for tid<168)
    const int s1v = tid & 1;
    const int k0q = s1v * 32;
    const int g4 = (node * 3121) >> 16;         // node/21
    const int p  = node - 21 * g4;
    const int dist  = (p == 0) ? 0 : (((p & 3) == 1) ? p : 1);
    const float cw  = ((p & 3) == 1) ? INV_SQRT2 : 0.5f;
    const int jp = p - dist;
    const int dist2 = (jp == 0) ? 0 : (((jp & 3) == 1) ? jp : 1);
    const float cw2 = ((jp & 3) == 1) ? INV_SQRT2 : 0.5f;
    const int xoff = node * 3;
    char* const fragW = sFrag + ((p >> 2) * 2 + s1v) * TSTRIDE
                      + (4 * g4 + (p & 3)) * 16;

    // cross-barrier carry: NAMED uint4s only (no arrays -> no demotion)
    uint4 c0_, c1_, c2_, c3_;

    auto p1_compute = [&](int buf) {
        const float* xs = (const float*)&sX[buf][0] + xoff;
        const float* xq = xs - dist * 3;
        const float* xg = xq - dist2 * 3;
        const float ax0 = fmaf(cw,  xq[0], 0.5f * xs[0]);
        const float ax1 = fmaf(cw,  xq[1], 0.5f * xs[1]);
        const float ax2 = fmaf(cw,  xq[2], 0.5f * xs[2]);
        const float bx0 = fmaf(cw2, xg[0], 0.5f * xq[0]);
        const float bx1 = fmaf(cw2, xg[1], 0.5f * xq[1]);
        const float bx2 = fmaf(cw2, xg[2], 0.5f * xq[2]);
        unsigned u0, u1, u2, u3, u4, u5, u6, u7;
        unsigned u8, u9, u10, u11, u12, u13, u14, u15;
        PKPAIR(0,  u0);  PKPAIR(1,  u1);  PKPAIR(2,  u2);  PKPAIR(3,  u3);
        PKPAIR(4,  u4);  PKPAIR(5,  u5);  PKPAIR(6,  u6);  PKPAIR(7,  u7);
        PKPAIR(8,  u8);  PKPAIR(9,  u9);  PKPAIR(10, u10); PKPAIR(11, u11);
        PKPAIR(12, u12); PKPAIR(13, u13); PKPAIR(14, u14); PKPAIR(15, u15);
        c0_ = make_uint4(u0,  u1,  u2,  u3);
        c1_ = make_uint4(u4,  u5,  u6,  u7);
        c2_ = make_uint4(u8,  u9,  u10, u11);
        c3_ = make_uint4(u12, u13, u14, u15);
    };
    auto p1_write = [&]() {
        *(uint4*)(fragW + 0 * 256) = c0_;
        *(uint4*)(fragW + 1 * 256) = c1_;
        *(uint4*)(fragW + 2 * 256) = c2_;
        *(uint4*)(fragW + 3 * 256) = c3_;
    };

    auto mfma_pool = [&]() {
        const char* fragA = sFrag + lane * 16;
        float pg0 = 0.f, pg1 = 0.f;
        #pragma unroll
        for (int m = 0; m < 6; ++m) {
            const s16x8 A0 = *(const s16x8*)(fragA + (2*m + 0) * TSTRIDE);
            const s16x8 A1 = *(const s16x8*)(fragA + (2*m + 1) * TSTRIDE);
            f32x4 acc0 = {0.f, 0.f, 0.f, 0.f};
            f32x4 acc1 = {0.f, 0.f, 0.f, 0.f};
            acc0 = __builtin_amdgcn_mfma_f32_16x16x32_bf16(A0, *(const s16x8*)&B00, acc0, 0, 0, 0);
            acc0 = __builtin_amdgcn_mfma_f32_16x16x32_bf16(A1, *(const s16x8*)&B01, acc0, 0, 0, 0);
            acc1 = __builtin_amdgcn_mfma_f32_16x16x32_bf16(A0, *(const s16x8*)&B10, acc1, 0, 0, 0);
            acc1 = __builtin_amdgcn_mfma_f32_16x16x32_bf16(A1, *(const s16x8*)&B11, acc1, 0, 0, 0);
            #pragma unroll
            for (int i = 0; i < 4; ++i) {
                const int pp = 4*m + i;
                if (pp < 21) {
                    const float wgt = (pp == 0) ? ROOT_W
                                    : (((pp & 3) == 0) ? (0.5f / 21.f) : (1.f / 21.f));
                    pg0 = fmaf(wgt, fmaxf(acc0[i] + b2c0, 0.f), pg0);
                    pg1 = fmaf(wgt, fmaxf(acc1[i] + b2c1, 0.f), pg1);
                }
            }
        }
        sPool[lg * 132 + 32*w + r]      = pg0;
        sPool[lg * 132 + 32*w + 16 + r] = pg1;
    };

    auto p3_out = [&](int ck) {
        float v = -1e30f;
        if (lane < 2 * NCLS) {
            const float4* pp = (const float4*)&sPool[w * 132 + 64 * h3];
            const float4* w3 = (const float4*)w3base;
            float acc3 = 0.f;
            #pragma unroll
            for (int q = 0; q < 16; ++q) {
                const float4 pv = pp[q];
                const float4 wv = w3[q];
                acc3 = fmaf(pv.x, wv.x, acc3);
                acc3 = fmaf(pv.y, wv.y, acc3);
                acc3 = fmaf(pv.z, wv.z, acc3);
                acc3 = fmaf(pv.w, wv.w, acc3);
            }
            v = acc3;
        }
        v += __shfl_xor(v, 1);              // combine k-halves -> full 128-dot
        if (lane < 2 * NCLS) v += b3r;
        float m = v;
        m = fmaxf(m, __shfl_xor(m, 2));
        m = fmaxf(m, __shfl_xor(m, 4));
        m = fmaxf(m, __shfl_xor(m, 8));
        m = fmaxf(m, __shfl_xor(m, 16));
        m = fmaxf(m, __shfl_xor(m, 32));
        float e = (lane < 2 * NCLS) ? __expf(v - m) : 0.f;
        float ss = e;
        ss += __shfl_xor(ss, 2);
        ss += __shfl_xor(ss, 4);
        ss += __shfl_xor(ss, 8);
        ss += __shfl_xor(ss, 16);
        ss += __shfl_xor(ss, 32);
        if (h3 == 0 && lane < 2 * NCLS)
            out[((cbase + ck) * GPB + w) * NCLS + cc] = v - m - __logf(ss);
    };

    __syncthreads();                        // staging done
    if (tid < 168) { p1_compute(0); p1_write(); }
    __syncthreads();                        // frag[0] ready

    // ---- chunk 0 ----
    mfma_pool();                            // MFMA on frag[0]
    if (tid < 168) p1_compute(1);           // overlapped VALU (named regs only)
    __syncthreads();                        // MFMA reads done, pool[0] ready
    if (tid < 168) p1_write();              // frag <- chunk1
    p3_out(0);
    __syncthreads();                        // frag[1] ready, pool reads done

    // ---- chunk 1 ----
    mfma_pool();
    __syncthreads();                        // pool[1] ready
    p3_out(1);
}

extern "C" void kernel_launch(void* const* d_in, const int* in_sizes, int n_in,
                              void* d_out, int out_size, void* d_ws, size_t ws_size,
                              hipStream_t stream) {
    const float* x   = (const float*)d_in[0];
    const float* W1  = (const float*)d_in[1];
    const float* b1  = (const float*)d_in[2];
    const float* g1  = (const float*)d_in[3];
    const float* be1 = (const float*)d_in[4];
    const float* m1  = (const float*)d_in[5];
    const float* v1  = (const float*)d_in[6];
    const float* W2  = (const float*)d_in[7];
    const float* b2  = (const float*)d_in[8];
    const float* g2  = (const float*)d_in[9];
    const float* be2 = (const float*)d_in[10];
    const float* m2  = (const float*)d_in[11];
    const float* v2  = (const float*)d_in[12];
    const float* W3  = (const float*)d_in[13];
    const float* b3  = (const float*)d_in[14];
    float* out = (float*)d_out;
    float* ws  = (float*)d_ws;

    prep_kernel<<<(WS_TOTAL + 255) / 256, 256, 0, stream>>>(
        W1, b1, g1, be1, m1, v1, W2, b2, g2, be2, m2, v2, W3, b3, ws);

    gcn_main<<<NBLK, 256, 0, stream>>>(x, ws, out);
}